// Round 12
// baseline (308.403 us; speedup 1.0000x reference)
//
#include <hip/hip_runtime.h>

#define IN_CH 128
#define HID 64
#define OUT_CH 32
#define SLOT_CAP 64   // per-node edge slots; Poisson(16) tail past 64 ~ 1e-20

typedef _Float16 f16x8 __attribute__((ext_vector_type(8)));
typedef float f32x4 __attribute__((ext_vector_type(4)));

// ---------------------------------------------------------------------------
// bf16 helpers (RNE)
// ---------------------------------------------------------------------------
__device__ __forceinline__ unsigned short f32_to_bf16(float f) {
    union { float f; unsigned int u; } v; v.f = f;
    unsigned int u = v.u;
    u += 0x7FFFu + ((u >> 16) & 1u);
    return (unsigned short)(u >> 16);
}
__device__ __forceinline__ float bf16_to_f32(unsigned short h) {
    union { unsigned int u; float f; } v; v.u = ((unsigned int)h) << 16;
    return v.f;
}
__device__ __forceinline__ float bf16_lo(unsigned int u) {
    union { unsigned int u; float f; } v; v.u = u << 16; return v.f;
}
__device__ __forceinline__ float bf16_hi(unsigned int u) {
    union { unsigned int u; float f; } v; v.u = u & 0xFFFF0000u; return v.f;
}

// ---------------------------------------------------------------------------
// edge_index: int64 in reference; int32 possible from harness.
// ---------------------------------------------------------------------------
__device__ __forceinline__ int load_idx(const void* e, long long i, int is64) {
    if (is64) return ((const int*)e)[2 * i];  // little-endian low word
    return ((const int*)e)[i];
}

// ---------------------------------------------------------------------------
// edgebin: ONE-PASS direct scatter replacing binA+binB (r11: two edge passes
// + LDS hist + 256-scan + sort, ~38 us). Every node owns a fixed 64-slot
// segment of es; slot index from a device-scope atomicAdd on cnt[dst]
// (1.6M atomics over 100k counters -> ~16/address, L2-side ALUs, ~5 us).
// cnt[] doubles as the degree for dinv = rsqrt(cnt+1), computed by each
// consumer (no dinv array). Edge weight stays factored (r10-verified):
// dinv[src] folded into pre-scaled GEMM outputs, dinv[dst] in the gather
// epilogue, so es needs ONLY src (4 B/edge). int64-vs-int32 detection via
// wave-0 ballot over the first 64 high words.
// ---------------------------------------------------------------------------
__global__ __launch_bounds__(256) void edgebin_kernel(
    const void* __restrict__ edges, long long E,
    int* __restrict__ cnt, int* __restrict__ es) {
    __shared__ int s_is64;
    const int tid = threadIdx.x;
    if (tid < 64) {
        int v = ((const int*)edges)[2 * tid + 1];
        unsigned long long nz = __ballot(v != 0);
        if (tid == 0) s_is64 = (nz == 0ull) ? 1 : 0;
    }
    __syncthreads();
    const int is64 = s_is64;

    const long long stride = (long long)gridDim.x * 256;
    for (long long i = (long long)blockIdx.x * 256 + tid; i < E; i += stride) {
        int src = load_idx(edges, i, is64);
        int dst = load_idx(edges, E + i, is64);
        int slot = atomicAdd(&cnt[dst], 1);
        if (slot < SLOT_CAP)
            es[((long long)dst << 6) + slot] = src;
    }
}

// ---------------------------------------------------------------------------
// GEMM1 via MFMA f16: m1s = (x @ W1) * dinv[row], bf16, row-major [n][64].
// dinv computed in-epilogue from cnt. fp32 accumulate; f16 input rounding
// << bf16 output quantization. One wave = one 16-row x 64-col tile: 16 mfma.
// ZERO LDS/barriers. (Needs cnt -> after edgebin.)
// ---------------------------------------------------------------------------
__global__ __launch_bounds__(256) void gemm1_kernel(
    const float* __restrict__ x, const float* __restrict__ W1,
    const int* __restrict__ cnt, unsigned short* __restrict__ m1s, int n) {
    const int lane = threadIdx.x & 63;
    const int wid  = threadIdx.x >> 6;
    const int m    = lane & 15;   // A-row / B-col / D-col within tile
    const int g    = lane >> 4;   // k-group (and D row-group)
    const int Rw   = blockIdx.x * 64 + wid * 16;

    // B fragments: wf[c][t][j] = W1[t*32 + g*8 + j][c*16 + m]
    f16x8 wf[4][4];
#pragma unroll
    for (int t = 0; t < 4; ++t) {
        const float* wp = W1 + (t * 32 + g * 8) * HID + m;
#pragma unroll
        for (int c = 0; c < 4; ++c) {
#pragma unroll
            for (int j = 0; j < 8; ++j)
                wf[c][t][j] = (_Float16)wp[j * HID + c * 16];
        }
    }

    int rl = Rw + m;
    if (rl >= n) rl = n - 1;   // clamp loads; stores guarded below
    const float* xr = x + (long long)rl * IN_CH;

    f32x4 acc[4] = {};

#pragma unroll
    for (int t = 0; t < 4; ++t) {
        float4 xa = *(const float4*)(xr + t * 32 + g * 8);
        float4 xb = *(const float4*)(xr + t * 32 + g * 8 + 4);
        f16x8 af;
        af[0] = (_Float16)xa.x; af[1] = (_Float16)xa.y;
        af[2] = (_Float16)xa.z; af[3] = (_Float16)xa.w;
        af[4] = (_Float16)xb.x; af[5] = (_Float16)xb.y;
        af[6] = (_Float16)xb.z; af[7] = (_Float16)xb.w;
#pragma unroll
        for (int c = 0; c < 4; ++c)
            acc[c] = __builtin_amdgcn_mfma_f32_16x16x32_f16(af, wf[c][t], acc[c], 0, 0, 0);
    }

#pragma unroll
    for (int r = 0; r < 4; ++r) {
        int row = Rw + g * 4 + r;
        if (row < n) {
            float dd = rsqrtf((float)cnt[row] + 1.0f);
#pragma unroll
            for (int c = 0; c < 4; ++c)
                m1s[(long long)row * HID + c * 16 + m] = f32_to_bf16(acc[c][r] * dd);
        }
    }
}

// ---------------------------------------------------------------------------
// GEMM2 (register-tiled): m2s = (h @ W2) * dinv[row], bf16 in AND out,
// row-major [n][32]. h (bf16) staged to LDS as fp32 transposed.
// ---------------------------------------------------------------------------
#define PADH 132
__global__ __launch_bounds__(256) void gemm2_kernel(
    const unsigned short* __restrict__ hs, const float* __restrict__ W2,
    const int* __restrict__ cnt, unsigned short* __restrict__ m2s, int n) {
    __shared__ __align__(16) float sW[HID * OUT_CH];
    __shared__ __align__(16) float sH[HID * PADH];
    const int tid = threadIdx.x;

    {
        const float4* Wv = (const float4*)W2;
        float4* sWv = (float4*)sW;
        for (int i = tid; i < HID * OUT_CH / 4; i += 256) sWv[i] = Wv[i];
    }

    const int R0 = blockIdx.x * 128;
    for (int i = tid; i < 128 * 8; i += 256) {
        int r = i >> 3;
        int q = i & 7;
        int row = R0 + r;
        uint4 v = make_uint4(0u, 0u, 0u, 0u);
        if (row < n)
            v = ((const uint4*)(hs + (long long)row * HID))[q];
        int k0 = q * 8;
        sH[(k0 + 0) * PADH + r] = bf16_lo(v.x);
        sH[(k0 + 1) * PADH + r] = bf16_hi(v.x);
        sH[(k0 + 2) * PADH + r] = bf16_lo(v.y);
        sH[(k0 + 3) * PADH + r] = bf16_hi(v.y);
        sH[(k0 + 4) * PADH + r] = bf16_lo(v.z);
        sH[(k0 + 5) * PADH + r] = bf16_hi(v.z);
        sH[(k0 + 6) * PADH + r] = bf16_lo(v.w);
        sH[(k0 + 7) * PADH + r] = bf16_hi(v.w);
    }
    __syncthreads();

    const int tx = tid & 7;
    const int ty = tid >> 3;
    float acc[4][4] = {};
    const float* pH = sH + ty * 4;
    const float* pW = sW + tx * 4;
#pragma unroll 8
    for (int k = 0; k < HID; ++k) {
        float4 hv = *(const float4*)(pH + k * PADH);
        float4 wv = *(const float4*)(pW + k * OUT_CH);
        acc[0][0] += hv.x * wv.x; acc[0][1] += hv.x * wv.y;
        acc[0][2] += hv.x * wv.z; acc[0][3] += hv.x * wv.w;
        acc[1][0] += hv.y * wv.x; acc[1][1] += hv.y * wv.y;
        acc[1][2] += hv.y * wv.z; acc[1][3] += hv.y * wv.w;
        acc[2][0] += hv.z * wv.x; acc[2][1] += hv.z * wv.y;
        acc[2][2] += hv.z * wv.z; acc[2][3] += hv.z * wv.w;
        acc[3][0] += hv.w * wv.x; acc[3][1] += hv.w * wv.y;
        acc[3][2] += hv.w * wv.z; acc[3][3] += hv.w * wv.w;
    }

#pragma unroll
    for (int i = 0; i < 4; ++i) {
        int row = R0 + ty * 4 + i;
        if (row < n) {
            float dd = rsqrtf((float)cnt[row] + 1.0f);
            ushort4 o;
            o.x = f32_to_bf16(acc[i][0] * dd);
            o.y = f32_to_bf16(acc[i][1] * dd);
            o.z = f32_to_bf16(acc[i][2] * dd);
            o.w = f32_to_bf16(acc[i][3] * dd);
            *(ushort4*)(m2s + (long long)row * OUT_CH + tx * 4) = o;
        }
    }
}

// ---------------------------------------------------------------------------
// Gather layer 1 (quarter-wave + fixed-stride es): QUARTER-WAVE = one node;
// lane-in-quarter l=0..15 owns channels 4l..4l+3 (uint2 = 4 bf16). 4 nodes
// per wave -> 4 distinct rows per gather instruction; full 128-B row
// consumed per line. es row = node<<6 (no row_off load). Epilogue:
// (acc + self) * rsqrt(cnt+1) + b1, ReLU, bf16x4 store.
// ---------------------------------------------------------------------------
__global__ __launch_bounds__(256) void gather64_kernel(
    const int* __restrict__ cnt, const int* __restrict__ es,
    const unsigned short* __restrict__ m1s, const float* __restrict__ b1,
    unsigned short* __restrict__ hs, int n) {
    const int node = blockIdx.x * 16 + (threadIdx.x >> 4);
    const int l    = threadIdx.x & 15;   // channel quad: ch 4l..4l+3
    if (node >= n) return;
    const int start = node << 6;
    const int cfull = cnt[node];
    const int c     = (cfull < SLOT_CAP) ? cfull : SLOT_CAP;

    float a0 = 0.f, a1 = 0.f, a2 = 0.f, a3 = 0.f;
    int j = 0;
    for (; j + 15 < c; j += 16) {
        int s[16];
#pragma unroll
        for (int u = 0; u < 16; ++u) s[u] = es[start + j + u];
        uint2 v[16];
#pragma unroll
        for (int u = 0; u < 16; ++u)
            v[u] = *(const uint2*)(m1s + (unsigned)(s[u] * HID) + l * 4);
#pragma unroll
        for (int u = 0; u < 16; ++u) {
            a0 += bf16_lo(v[u].x); a1 += bf16_hi(v[u].x);
            a2 += bf16_lo(v[u].y); a3 += bf16_hi(v[u].y);
        }
    }
    for (; j + 7 < c; j += 8) {
        int s[8];
#pragma unroll
        for (int u = 0; u < 8; ++u) s[u] = es[start + j + u];
        uint2 v[8];
#pragma unroll
        for (int u = 0; u < 8; ++u)
            v[u] = *(const uint2*)(m1s + (unsigned)(s[u] * HID) + l * 4);
#pragma unroll
        for (int u = 0; u < 8; ++u) {
            a0 += bf16_lo(v[u].x); a1 += bf16_hi(v[u].x);
            a2 += bf16_lo(v[u].y); a3 += bf16_hi(v[u].y);
        }
    }
    for (; j + 3 < c; j += 4) {
        int s[4];
#pragma unroll
        for (int u = 0; u < 4; ++u) s[u] = es[start + j + u];
        uint2 v[4];
#pragma unroll
        for (int u = 0; u < 4; ++u)
            v[u] = *(const uint2*)(m1s + (unsigned)(s[u] * HID) + l * 4);
#pragma unroll
        for (int u = 0; u < 4; ++u) {
            a0 += bf16_lo(v[u].x); a1 += bf16_hi(v[u].x);
            a2 += bf16_lo(v[u].y); a3 += bf16_hi(v[u].y);
        }
    }
    for (; j < c; ++j) {
        int s = es[start + j];
        uint2 v = *(const uint2*)(m1s + (unsigned)(s * HID) + l * 4);
        a0 += bf16_lo(v.x); a1 += bf16_hi(v.x);
        a2 += bf16_lo(v.y); a3 += bf16_hi(v.y);
    }

    float dd = rsqrtf((float)cfull + 1.0f);
    uint2 sv = *(const uint2*)(m1s + (unsigned)(node * HID) + l * 4);
    float4 bv = *(const float4*)(b1 + l * 4);
    ushort4 o;
    o.x = f32_to_bf16(fmaxf((a0 + bf16_lo(sv.x)) * dd + bv.x, 0.f));
    o.y = f32_to_bf16(fmaxf((a1 + bf16_hi(sv.x)) * dd + bv.y, 0.f));
    o.z = f32_to_bf16(fmaxf((a2 + bf16_lo(sv.y)) * dd + bv.z, 0.f));
    o.w = f32_to_bf16(fmaxf((a3 + bf16_hi(sv.y)) * dd + bv.w, 0.f));
    *(ushort4*)(hs + (unsigned)(node * HID) + l * 4) = o;
}

// ---------------------------------------------------------------------------
// Gather layer 2 (quarter-wave + fixed-stride es): lane-in-quarter l owns
// channels 2l,2l+1 (uint). 4 distinct 64-B rows per gather instruction.
// Epilogue: (acc + self) * rsqrt(cnt+1) + b2; float2 store.
// ---------------------------------------------------------------------------
__global__ __launch_bounds__(256) void gather32_kernel(
    const int* __restrict__ cnt, const int* __restrict__ es,
    const unsigned short* __restrict__ m2s, const float* __restrict__ b2,
    float* __restrict__ out, int n) {
    const int node = blockIdx.x * 16 + (threadIdx.x >> 4);
    const int l    = threadIdx.x & 15;   // channel pair: ch 2l, 2l+1
    if (node >= n) return;
    const int start = node << 6;
    const int cfull = cnt[node];
    const int c     = (cfull < SLOT_CAP) ? cfull : SLOT_CAP;

    float a0 = 0.f, a1 = 0.f;
    int j = 0;
    for (; j + 15 < c; j += 16) {
        int s[16];
#pragma unroll
        for (int u = 0; u < 16; ++u) s[u] = es[start + j + u];
        unsigned v[16];
#pragma unroll
        for (int u = 0; u < 16; ++u)
            v[u] = *(const unsigned*)(m2s + (unsigned)(s[u] * OUT_CH) + l * 2);
#pragma unroll
        for (int u = 0; u < 16; ++u) {
            a0 += bf16_lo(v[u]);
            a1 += bf16_hi(v[u]);
        }
    }
    for (; j + 7 < c; j += 8) {
        int s[8];
#pragma unroll
        for (int u = 0; u < 8; ++u) s[u] = es[start + j + u];
        unsigned v[8];
#pragma unroll
        for (int u = 0; u < 8; ++u)
            v[u] = *(const unsigned*)(m2s + (unsigned)(s[u] * OUT_CH) + l * 2);
#pragma unroll
        for (int u = 0; u < 8; ++u) {
            a0 += bf16_lo(v[u]);
            a1 += bf16_hi(v[u]);
        }
    }
    for (; j + 3 < c; j += 4) {
        int s[4];
#pragma unroll
        for (int u = 0; u < 4; ++u) s[u] = es[start + j + u];
        unsigned v[4];
#pragma unroll
        for (int u = 0; u < 4; ++u)
            v[u] = *(const unsigned*)(m2s + (unsigned)(s[u] * OUT_CH) + l * 2);
#pragma unroll
        for (int u = 0; u < 4; ++u) {
            a0 += bf16_lo(v[u]);
            a1 += bf16_hi(v[u]);
        }
    }
    for (; j < c; ++j) {
        int s = es[start + j];
        unsigned v = *(const unsigned*)(m2s + (unsigned)(s * OUT_CH) + l * 2);
        a0 += bf16_lo(v);
        a1 += bf16_hi(v);
    }

    float dd = rsqrtf((float)cfull + 1.0f);
    unsigned sv = *(const unsigned*)(m2s + (unsigned)(node * OUT_CH) + l * 2);
    float2 o;
    o.x = (a0 + bf16_lo(sv)) * dd + b2[l * 2];
    o.y = (a1 + bf16_hi(sv)) * dd + b2[l * 2 + 1];
    *(float2*)(out + (unsigned)(node * OUT_CH) + l * 2) = o;
}

// ---------------------------------------------------------------------------
// Launch
// ---------------------------------------------------------------------------
extern "C" void kernel_launch(void* const* d_in, const int* in_sizes, int n_in,
                              void* d_out, int out_size, void* d_ws, size_t ws_size,
                              hipStream_t stream) {
    const float* x     = (const float*)d_in[0];
    const void*  edges = d_in[1];
    const float* W1    = (const float*)d_in[2];
    const float* b1    = (const float*)d_in[3];
    const float* W2    = (const float*)d_in[4];
    const float* b2    = (const float*)d_in[5];
    float* out = (float*)d_out;

    const int n = in_sizes[0] / IN_CH;              // 100000
    const long long E = (long long)in_sizes[1] / 2; // 1600000

    // Workspace (~58 MB): cnt[n] | es[n*64] | m1s[n*64 u16] | hs[n*64 u16] |
    // m2s[n*32 u16]
    int*   cnt           = (int*)d_ws;
    int*   es            = cnt + n;
    unsigned short* m1s  = (unsigned short*)(es + (size_t)n * SLOT_CAP);
    unsigned short* hs   = m1s + (size_t)n * HID;
    unsigned short* m2s  = hs + (size_t)n * HID;

    hipMemsetAsync(cnt, 0, (size_t)n * sizeof(int), stream);

    edgebin_kernel<<<2048, 256, 0, stream>>>(edges, E, cnt, es);

    // Layer 1 (gemm1 reads cnt for the dinv fold -> after edgebin)
    gemm1_kernel<<<(n + 63) / 64, 256, 0, stream>>>(x, W1, cnt, m1s, n);
    gather64_kernel<<<(n + 15) / 16, 256, 0, stream>>>(cnt, es, m1s, b1, hs, n);

    // Layer 2
    gemm2_kernel<<<(n + 127) / 128, 256, 0, stream>>>(hs, W2, cnt, m2s, n);
    gather32_kernel<<<(n + 15) / 16, 256, 0, stream>>>(cnt, es, m2s, b2, out, n);
}

// Round 13
// 226.717 us; speedup vs baseline: 1.3603x; 1.3603x over previous
//
#include <hip/hip_runtime.h>

#define IN_CH 128
#define HID 64
#define OUT_CH 32
#define BUCKET_CAP 6144   // mean 4096, sigma ~64 for this E/N; overflow-guarded
#define NB_MAX 512

typedef _Float16 f16x8 __attribute__((ext_vector_type(8)));
typedef float f32x4 __attribute__((ext_vector_type(4)));

// ---------------------------------------------------------------------------
// bf16 helpers (RNE)
// ---------------------------------------------------------------------------
__device__ __forceinline__ unsigned short f32_to_bf16(float f) {
    union { float f; unsigned int u; } v; v.f = f;
    unsigned int u = v.u;
    u += 0x7FFFu + ((u >> 16) & 1u);
    return (unsigned short)(u >> 16);
}
__device__ __forceinline__ float bf16_to_f32(unsigned short h) {
    union { unsigned int u; float f; } v; v.u = ((unsigned int)h) << 16;
    return v.f;
}
__device__ __forceinline__ float bf16_lo(unsigned int u) {
    union { unsigned int u; float f; } v; v.u = u << 16; return v.f;
}
__device__ __forceinline__ float bf16_hi(unsigned int u) {
    union { unsigned int u; float f; } v; v.u = u & 0xFFFF0000u; return v.f;
}

// ---------------------------------------------------------------------------
// edge_index: int64 in reference; int32 possible from harness.
// ---------------------------------------------------------------------------
__device__ __forceinline__ int load_idx(const void* e, long long i, int is64) {
    if (is64) return ((const int*)e)[2 * i];  // little-endian low word
    return ((const int*)e)[i];
}

// ---------------------------------------------------------------------------
// binA: LDS-binned bucketing of edges by dst>>8 into fixed-capacity buckets.
// entry = (src << 8) | (dst & 255). int64-vs-int32 detection fused here.
// NOTE (r12 lesson): this two-phase structure IS the write-coalescer — the
// one-pass direct scatter (4 B random stores) costs 97 MB of write-allocate
// traffic and 131 us. Keep the bucket machinery.
// ---------------------------------------------------------------------------
__global__ __launch_bounds__(256) void binA_kernel(
    const void* __restrict__ edges, long long E,
    int* __restrict__ bucket_cur, unsigned int* __restrict__ entries, int nb) {
    __shared__ int hist[NB_MAX];
    __shared__ int cbase[NB_MAX];
    __shared__ int s_is64;
    const int tid = threadIdx.x;

    if (tid < 64) {
        int v = ((const int*)edges)[2 * tid + 1];
        unsigned long long nz = __ballot(v != 0);
        if (tid == 0) s_is64 = (nz == 0ull) ? 1 : 0;
    }
    for (int i = tid; i < nb; i += 256) hist[i] = 0;
    __syncthreads();
    const int is64 = s_is64;

    const long long per = (E + gridDim.x - 1) / gridDim.x;
    const long long lo = blockIdx.x * per;
    const long long hi = (lo + per < E) ? lo + per : E;

    for (long long i = lo + tid; i < hi; i += 256) {
        int dst = load_idx(edges, E + i, is64);
        atomicAdd(&hist[dst >> 8], 1);
    }
    __syncthreads();
    for (int i = tid; i < nb; i += 256) {
        int c = hist[i];
        int base = (c > 0) ? atomicAdd(&bucket_cur[i], c) : 0;
        cbase[i] = base;
        hist[i] = 0;  // reuse as running local offset
    }
    __syncthreads();
    for (long long i = lo + tid; i < hi; i += 256) {
        int src = load_idx(edges, i, is64);
        int dst = load_idx(edges, E + i, is64);
        int b = dst >> 8;
        int rel = cbase[b] + atomicAdd(&hist[b], 1);
        if (rel < BUCKET_CAP)
            entries[(long long)b * BUCKET_CAP + rel] = ((unsigned)src << 8) | (unsigned)(dst & 255);
    }
}

// ---------------------------------------------------------------------------
// binB (merged B1+B2): block per bucket. Entries staged ONCE in LDS (24.6 KB),
// then: per-node hist -> scan -> counts/row_off/dinv, then node-sort into
// es[] = src-only (4 B/edge; the weight dinv[src]*dinv[dst] is factored:
// dinv[src] folded into the pre-scaled GEMM outputs, dinv[dst] applied once
// per node in the gather epilogue — numerics verified in r10, same absmax).
// ---------------------------------------------------------------------------
__global__ __launch_bounds__(256) void binB_kernel(
    const unsigned int* __restrict__ entries, const int* __restrict__ bucket_cur,
    int* __restrict__ counts, int* __restrict__ row_off, float* __restrict__ dinv,
    int* __restrict__ es, int n) {
    __shared__ int se[BUCKET_CAP];   // 24.6 KB
    __shared__ int hist[256];
    __shared__ int scan[256];
    const int b   = blockIdx.x;
    const int tid = threadIdx.x;
    const long long seg = (long long)b * BUCKET_CAP;
    int cnt = bucket_cur[b];
    if (cnt > BUCKET_CAP) cnt = BUCKET_CAP;

    for (int i = tid; i < cnt; i += 256) se[i] = (int)entries[seg + i];
    hist[tid] = 0;
    __syncthreads();

    for (int i = tid; i < cnt; i += 256)
        atomicAdd(&hist[se[i] & 255], 1);
    __syncthreads();

    int v = hist[tid];
    scan[tid] = v;
    __syncthreads();
    for (int off = 1; off < 256; off <<= 1) {
        int t = (tid >= off) ? scan[tid - off] : 0;
        __syncthreads();
        scan[tid] += t;
        __syncthreads();
    }
    int ex = scan[tid] - v;
    int node = (b << 8) + tid;
    if (node < n) {
        counts[node]  = v;
        row_off[node] = (int)seg + ex;
        dinv[node]    = rsqrtf((float)v + 1.0f);  // +1 self-loop
    }
    hist[tid] = ex;   // reuse as running write cursor
    __syncthreads();

    for (int i = tid; i < cnt; i += 256) {
        int e = se[i];
        int d = e & 255;
        int s = e >> 8;
        int r = atomicAdd(&hist[d], 1);
        es[seg + r] = s;
    }
}

// ---------------------------------------------------------------------------
// GEMM1 via MFMA f16: m1s = (x @ W1) * dinv[row], bf16, row-major [n][64].
// fp32 accumulate; f16 input rounding << bf16 output quantization. One wave
// = one 16-row x 64-col tile: 16 mfma. ZERO LDS/barriers. (After binB: dinv.)
// ---------------------------------------------------------------------------
__global__ __launch_bounds__(256) void gemm1_kernel(
    const float* __restrict__ x, const float* __restrict__ W1,
    const float* __restrict__ dinv, unsigned short* __restrict__ m1s, int n) {
    const int lane = threadIdx.x & 63;
    const int wid  = threadIdx.x >> 6;
    const int m    = lane & 15;   // A-row / B-col / D-col within tile
    const int g    = lane >> 4;   // k-group (and D row-group)
    const int Rw   = blockIdx.x * 64 + wid * 16;

    // B fragments: wf[c][t][j] = W1[t*32 + g*8 + j][c*16 + m]
    f16x8 wf[4][4];
#pragma unroll
    for (int t = 0; t < 4; ++t) {
        const float* wp = W1 + (t * 32 + g * 8) * HID + m;
#pragma unroll
        for (int c = 0; c < 4; ++c) {
#pragma unroll
            for (int j = 0; j < 8; ++j)
                wf[c][t][j] = (_Float16)wp[j * HID + c * 16];
        }
    }

    int rl = Rw + m;
    if (rl >= n) rl = n - 1;   // clamp loads; stores guarded below
    const float* xr = x + (long long)rl * IN_CH;

    f32x4 acc[4] = {};

#pragma unroll
    for (int t = 0; t < 4; ++t) {
        float4 xa = *(const float4*)(xr + t * 32 + g * 8);
        float4 xb = *(const float4*)(xr + t * 32 + g * 8 + 4);
        f16x8 af;
        af[0] = (_Float16)xa.x; af[1] = (_Float16)xa.y;
        af[2] = (_Float16)xa.z; af[3] = (_Float16)xa.w;
        af[4] = (_Float16)xb.x; af[5] = (_Float16)xb.y;
        af[6] = (_Float16)xb.z; af[7] = (_Float16)xb.w;
#pragma unroll
        for (int c = 0; c < 4; ++c)
            acc[c] = __builtin_amdgcn_mfma_f32_16x16x32_f16(af, wf[c][t], acc[c], 0, 0, 0);
    }

#pragma unroll
    for (int r = 0; r < 4; ++r) {
        int row = Rw + g * 4 + r;
        if (row < n) {
            float dd = dinv[row];
#pragma unroll
            for (int c = 0; c < 4; ++c)
                m1s[(long long)row * HID + c * 16 + m] = f32_to_bf16(acc[c][r] * dd);
        }
    }
}

// ---------------------------------------------------------------------------
// GEMM2 (register-tiled): m2s = (h @ W2) * dinv[row], bf16 in AND out,
// row-major [n][32]. h (bf16) staged to LDS as fp32 transposed.
// ---------------------------------------------------------------------------
#define PADH 132
__global__ __launch_bounds__(256) void gemm2_kernel(
    const unsigned short* __restrict__ hs, const float* __restrict__ W2,
    const float* __restrict__ dinv, unsigned short* __restrict__ m2s, int n) {
    __shared__ __align__(16) float sW[HID * OUT_CH];
    __shared__ __align__(16) float sH[HID * PADH];
    const int tid = threadIdx.x;

    {
        const float4* Wv = (const float4*)W2;
        float4* sWv = (float4*)sW;
        for (int i = tid; i < HID * OUT_CH / 4; i += 256) sWv[i] = Wv[i];
    }

    const int R0 = blockIdx.x * 128;
    for (int i = tid; i < 128 * 8; i += 256) {
        int r = i >> 3;
        int q = i & 7;
        int row = R0 + r;
        uint4 v = make_uint4(0u, 0u, 0u, 0u);
        if (row < n)
            v = ((const uint4*)(hs + (long long)row * HID))[q];
        int k0 = q * 8;
        sH[(k0 + 0) * PADH + r] = bf16_lo(v.x);
        sH[(k0 + 1) * PADH + r] = bf16_hi(v.x);
        sH[(k0 + 2) * PADH + r] = bf16_lo(v.y);
        sH[(k0 + 3) * PADH + r] = bf16_hi(v.y);
        sH[(k0 + 4) * PADH + r] = bf16_lo(v.z);
        sH[(k0 + 5) * PADH + r] = bf16_hi(v.z);
        sH[(k0 + 6) * PADH + r] = bf16_lo(v.w);
        sH[(k0 + 7) * PADH + r] = bf16_hi(v.w);
    }
    __syncthreads();

    const int tx = tid & 7;
    const int ty = tid >> 3;
    float acc[4][4] = {};
    const float* pH = sH + ty * 4;
    const float* pW = sW + tx * 4;
#pragma unroll 8
    for (int k = 0; k < HID; ++k) {
        float4 hv = *(const float4*)(pH + k * PADH);
        float4 wv = *(const float4*)(pW + k * OUT_CH);
        acc[0][0] += hv.x * wv.x; acc[0][1] += hv.x * wv.y;
        acc[0][2] += hv.x * wv.z; acc[0][3] += hv.x * wv.w;
        acc[1][0] += hv.y * wv.x; acc[1][1] += hv.y * wv.y;
        acc[1][2] += hv.y * wv.z; acc[1][3] += hv.y * wv.w;
        acc[2][0] += hv.z * wv.x; acc[2][1] += hv.z * wv.y;
        acc[2][2] += hv.z * wv.z; acc[2][3] += hv.z * wv.w;
        acc[3][0] += hv.w * wv.x; acc[3][1] += hv.w * wv.y;
        acc[3][2] += hv.w * wv.z; acc[3][3] += hv.w * wv.w;
    }

#pragma unroll
    for (int i = 0; i < 4; ++i) {
        int row = R0 + ty * 4 + i;
        if (row < n) {
            float dd = dinv[row];
            ushort4 o;
            o.x = f32_to_bf16(acc[i][0] * dd);
            o.y = f32_to_bf16(acc[i][1] * dd);
            o.z = f32_to_bf16(acc[i][2] * dd);
            o.w = f32_to_bf16(acc[i][3] * dd);
            *(ushort4*)(m2s + (long long)row * OUT_CH + tx * 4) = o;
        }
    }
}

// ---------------------------------------------------------------------------
// Gather layer 1 (quarter-wave + src-only stream): QUARTER-WAVE = one node;
// lane-in-quarter l=0..15 owns channels 4l..4l+3 (uint2 = 4 bf16).
// 4 nodes/wave -> 4 distinct rows per gather instruction; full 128-B row
// consumed per line. es stream 4 B/edge, no per-edge mul.
// Epilogue: (acc + self) * dinv[node] + b1, ReLU, bf16x4 store.
// ---------------------------------------------------------------------------
__global__ __launch_bounds__(256) void gather64_kernel(
    const int* __restrict__ row_off, const int* __restrict__ counts,
    const int* __restrict__ es, const float* __restrict__ dinv,
    const unsigned short* __restrict__ m1s, const float* __restrict__ b1,
    unsigned short* __restrict__ hs, int n) {
    const int node = blockIdx.x * 16 + (threadIdx.x >> 4);
    const int l    = threadIdx.x & 15;   // channel quad: ch 4l..4l+3
    if (node >= n) return;
    const int start = row_off[node];
    const int cnt   = counts[node];

    float a0 = 0.f, a1 = 0.f, a2 = 0.f, a3 = 0.f;
    int j = 0;
    for (; j + 15 < cnt; j += 16) {
        int s[16];
#pragma unroll
        for (int u = 0; u < 16; ++u) s[u] = es[start + j + u];
        uint2 v[16];
#pragma unroll
        for (int u = 0; u < 16; ++u)
            v[u] = *(const uint2*)(m1s + (unsigned)(s[u] * HID) + l * 4);
#pragma unroll
        for (int u = 0; u < 16; ++u) {
            a0 += bf16_lo(v[u].x); a1 += bf16_hi(v[u].x);
            a2 += bf16_lo(v[u].y); a3 += bf16_hi(v[u].y);
        }
    }
    for (; j + 7 < cnt; j += 8) {
        int s[8];
#pragma unroll
        for (int u = 0; u < 8; ++u) s[u] = es[start + j + u];
        uint2 v[8];
#pragma unroll
        for (int u = 0; u < 8; ++u)
            v[u] = *(const uint2*)(m1s + (unsigned)(s[u] * HID) + l * 4);
#pragma unroll
        for (int u = 0; u < 8; ++u) {
            a0 += bf16_lo(v[u].x); a1 += bf16_hi(v[u].x);
            a2 += bf16_lo(v[u].y); a3 += bf16_hi(v[u].y);
        }
    }
    for (; j + 3 < cnt; j += 4) {
        int s[4];
#pragma unroll
        for (int u = 0; u < 4; ++u) s[u] = es[start + j + u];
        uint2 v[4];
#pragma unroll
        for (int u = 0; u < 4; ++u)
            v[u] = *(const uint2*)(m1s + (unsigned)(s[u] * HID) + l * 4);
#pragma unroll
        for (int u = 0; u < 4; ++u) {
            a0 += bf16_lo(v[u].x); a1 += bf16_hi(v[u].x);
            a2 += bf16_lo(v[u].y); a3 += bf16_hi(v[u].y);
        }
    }
    for (; j < cnt; ++j) {
        int s = es[start + j];
        uint2 v = *(const uint2*)(m1s + (unsigned)(s * HID) + l * 4);
        a0 += bf16_lo(v.x); a1 += bf16_hi(v.x);
        a2 += bf16_lo(v.y); a3 += bf16_hi(v.y);
    }

    float dd = dinv[node];
    uint2 sv = *(const uint2*)(m1s + (unsigned)(node * HID) + l * 4);
    float4 bv = *(const float4*)(b1 + l * 4);
    ushort4 o;
    o.x = f32_to_bf16(fmaxf((a0 + bf16_lo(sv.x)) * dd + bv.x, 0.f));
    o.y = f32_to_bf16(fmaxf((a1 + bf16_hi(sv.x)) * dd + bv.y, 0.f));
    o.z = f32_to_bf16(fmaxf((a2 + bf16_lo(sv.y)) * dd + bv.z, 0.f));
    o.w = f32_to_bf16(fmaxf((a3 + bf16_hi(sv.y)) * dd + bv.w, 0.f));
    *(ushort4*)(hs + (unsigned)(node * HID) + l * 4) = o;
}

// ---------------------------------------------------------------------------
// Gather layer 2 (quarter-wave + src-only stream): lane-in-quarter l owns
// channels 2l,2l+1 (uint). 4 distinct 64-B rows per gather instruction.
// Epilogue: (acc + self) * dinv[node] + b2; float2 store.
// ---------------------------------------------------------------------------
__global__ __launch_bounds__(256) void gather32_kernel(
    const int* __restrict__ row_off, const int* __restrict__ counts,
    const int* __restrict__ es, const float* __restrict__ dinv,
    const unsigned short* __restrict__ m2s, const float* __restrict__ b2,
    float* __restrict__ out, int n) {
    const int node = blockIdx.x * 16 + (threadIdx.x >> 4);
    const int l    = threadIdx.x & 15;   // channel pair: ch 2l, 2l+1
    if (node >= n) return;
    const int start = row_off[node];
    const int cnt   = counts[node];

    float a0 = 0.f, a1 = 0.f;
    int j = 0;
    for (; j + 15 < cnt; j += 16) {
        int s[16];
#pragma unroll
        for (int u = 0; u < 16; ++u) s[u] = es[start + j + u];
        unsigned v[16];
#pragma unroll
        for (int u = 0; u < 16; ++u)
            v[u] = *(const unsigned*)(m2s + (unsigned)(s[u] * OUT_CH) + l * 2);
#pragma unroll
        for (int u = 0; u < 16; ++u) {
            a0 += bf16_lo(v[u]);
            a1 += bf16_hi(v[u]);
        }
    }
    for (; j + 7 < cnt; j += 8) {
        int s[8];
#pragma unroll
        for (int u = 0; u < 8; ++u) s[u] = es[start + j + u];
        unsigned v[8];
#pragma unroll
        for (int u = 0; u < 8; ++u)
            v[u] = *(const unsigned*)(m2s + (unsigned)(s[u] * OUT_CH) + l * 2);
#pragma unroll
        for (int u = 0; u < 8; ++u) {
            a0 += bf16_lo(v[u]);
            a1 += bf16_hi(v[u]);
        }
    }
    for (; j + 3 < cnt; j += 4) {
        int s[4];
#pragma unroll
        for (int u = 0; u < 4; ++u) s[u] = es[start + j + u];
        unsigned v[4];
#pragma unroll
        for (int u = 0; u < 4; ++u)
            v[u] = *(const unsigned*)(m2s + (unsigned)(s[u] * OUT_CH) + l * 2);
#pragma unroll
        for (int u = 0; u < 4; ++u) {
            a0 += bf16_lo(v[u]);
            a1 += bf16_hi(v[u]);
        }
    }
    for (; j < cnt; ++j) {
        int s = es[start + j];
        unsigned v = *(const unsigned*)(m2s + (unsigned)(s * OUT_CH) + l * 2);
        a0 += bf16_lo(v);
        a1 += bf16_hi(v);
    }

    float dd = dinv[node];
    unsigned sv = *(const unsigned*)(m2s + (unsigned)(node * OUT_CH) + l * 2);
    float2 o;
    o.x = (a0 + bf16_lo(sv)) * dd + b2[l * 2];
    o.y = (a1 + bf16_hi(sv)) * dd + b2[l * 2 + 1];
    *(float2*)(out + (unsigned)(node * OUT_CH) + l * 2) = o;
}

// ---------------------------------------------------------------------------
// Launch
// ---------------------------------------------------------------------------
extern "C" void kernel_launch(void* const* d_in, const int* in_sizes, int n_in,
                              void* d_out, int out_size, void* d_ws, size_t ws_size,
                              hipStream_t stream) {
    const float* x     = (const float*)d_in[0];
    const void*  edges = d_in[1];
    const float* W1    = (const float*)d_in[2];
    const float* b1    = (const float*)d_in[3];
    const float* W2    = (const float*)d_in[4];
    const float* b2    = (const float*)d_in[5];
    float* out = (float*)d_out;

    const int n = in_sizes[0] / IN_CH;              // 100000
    const long long E = (long long)in_sizes[1] / 2; // 1600000
    const int nb = (n + 255) / 256;                 // 391 buckets
    const size_t cap = (size_t)nb * BUCKET_CAP;

    // Workspace (~55 MB): dinv[n] | counts[n] | row_off[n] | bucket_cur[512]
    // | entries[cap] | es[cap] | m1s[n*64 u16] | hs[n*64 u16] | m2s[n*32 u16]
    float* ws            = (float*)d_ws;
    float* dinv          = ws;
    int*   counts        = (int*)(ws + n);
    int*   row_off       = counts + n;
    int*   bucket_cur    = row_off + n;
    unsigned int* entries = (unsigned int*)(bucket_cur + NB_MAX);
    int*   es            = (int*)(entries + cap);
    unsigned short* m1s  = (unsigned short*)(es + cap);
    unsigned short* hs   = m1s + (size_t)n * HID;
    unsigned short* m2s  = hs + (size_t)n * HID;

    hipMemsetAsync(bucket_cur, 0, NB_MAX * sizeof(int), stream);

    binA_kernel<<<256, 256, 0, stream>>>(edges, E, bucket_cur, entries, nb);
    binB_kernel<<<nb, 256, 0, stream>>>(entries, bucket_cur, counts, row_off,
                                        dinv, es, n);

    // Layer 1 (gemm1 needs dinv -> after binB)
    gemm1_kernel<<<(n + 63) / 64, 256, 0, stream>>>(x, W1, dinv, m1s, n);
    gather64_kernel<<<(n + 15) / 16, 256, 0, stream>>>(
        row_off, counts, es, dinv, m1s, b1, hs, n);

    // Layer 2
    gemm2_kernel<<<(n + 127) / 128, 256, 0, stream>>>(hs, W2, dinv, m2s, n);
    gather32_kernel<<<(n + 15) / 16, 256, 0, stream>>>(
        row_off, counts, es, dinv, m2s, b2, out, n);
}